// Round 6
// baseline (549.725 us; speedup 1.0000x reference)
//
#include <hip/hip_runtime.h>

#define LEAKY 0.2f

typedef unsigned short ushort_t;
typedef __attribute__((ext_vector_type(8))) short short8;
typedef __attribute__((ext_vector_type(4))) float f32x4;

__device__ __forceinline__ unsigned short f2bf(float f) {
  unsigned u = __float_as_uint(f);
  unsigned r = (u + 0x7fff + ((u >> 16) & 1)) >> 16;  // RNE
  return (unsigned short)r;
}
__device__ __forceinline__ float bf2f(unsigned short u) {
  return __uint_as_float(((unsigned)u) << 16);
}

// ---------------- CSR build ----------------
__global__ void count_k(const int* __restrict__ dst, int* __restrict__ cnt, int E) {
  int i = blockIdx.x * blockDim.x + threadIdx.x;
  if (i < E) atomicAdd(&cnt[dst[i]], 1);
}

__global__ __launch_bounds__(1024) void scan1_k(const int* __restrict__ cnt,
                                                int* __restrict__ ptr,
                                                int* __restrict__ bsum, int N) {
  int t = threadIdx.x;
  int i = blockIdx.x * 1024 + t;
  int v = (i < N) ? cnt[i] : 0;
  int lane = t & 63, w = t >> 6;
  int x = v;
  #pragma unroll
  for (int off = 1; off < 64; off <<= 1) {
    int y = __shfl_up(x, off, 64);
    if (lane >= off) x += y;
  }
  __shared__ int wsum[16];
  if (lane == 63) wsum[w] = x;
  __syncthreads();
  if (t < 16) {
    int s = wsum[t];
    #pragma unroll
    for (int off = 1; off < 16; off <<= 1) {
      int y = __shfl_up(s, off, 16);
      if (t >= off) s += y;
    }
    wsum[t] = s;
  }
  __syncthreads();
  int woff = (w > 0) ? wsum[w - 1] : 0;
  int incl = x + woff;
  if (i < N) ptr[i] = incl - v;
  if (t == 1023) bsum[blockIdx.x] = incl;
}

__global__ void scan2_k(int* __restrict__ bsum, int nb) {
  int t = threadIdx.x;
  int v = (t < nb) ? bsum[t] : 0;
  int x = v;
  #pragma unroll
  for (int off = 1; off < 64; off <<= 1) {
    int y = __shfl_up(x, off, 64);
    if (t >= off) x += y;
  }
  if (t < nb) bsum[t] = x - v;
}

__global__ __launch_bounds__(1024) void scan3_k(int* __restrict__ ptr,
                                                const int* __restrict__ bsum,
                                                int N, int E) {
  int i = blockIdx.x * 1024 + threadIdx.x;
  if (i < N) ptr[i] += bsum[blockIdx.x];
  if (i == 0) ptr[N] = E;
}

__global__ void fill_k(const int* __restrict__ dst, const int* __restrict__ ptr,
                       int* __restrict__ cur, int* __restrict__ eidx, int E) {
  int i = blockIdx.x * blockDim.x + threadIdx.x;
  if (i < E) {
    int d = dst[i];
    int p = atomicAdd(&cur[d], 1);
    eidx[ptr[d] + p] = i;
  }
}

// ---------------- W split+transpose: W[K][256] -> Wh/Wl[256][K] bf16 ----------------
__global__ void wsplit_k(const float* __restrict__ W, ushort_t* __restrict__ Wh,
                         ushort_t* __restrict__ Wl, int K) {
  int i = blockIdx.x * 256 + threadIdx.x;
  if (i >= 256 * K) return;
  int k = i % K, c = i / K;
  float x = W[(long)k * 256 + c];
  unsigned short hi = f2bf(x);
  Wh[i] = hi;
  Wl[i] = f2bf(x - bf2f(hi));
}

// ---------------- A split (row-major, no transpose): A_f32[N*K] -> Ah/Al bf16 ----------------
__global__ __launch_bounds__(256) void asplit_k(const float* __restrict__ A,
                                                ushort_t* __restrict__ Ah,
                                                ushort_t* __restrict__ Al, long total) {
  long i = ((long)blockIdx.x * 256 + threadIdx.x) * 4;
  if (i >= total) return;
  float4 v = *(const float4*)(A + i);
  unsigned short h0 = f2bf(v.x), h1 = f2bf(v.y), h2 = f2bf(v.z), h3 = f2bf(v.w);
  ushort4 hi = make_ushort4(h0, h1, h2, h3);
  ushort4 lo = make_ushort4(f2bf(v.x - bf2f(h0)), f2bf(v.y - bf2f(h1)),
                            f2bf(v.z - bf2f(h2)), f2bf(v.w - bf2f(h3)));
  *(ushort4*)(Ah + i) = hi;
  *(ushort4*)(Al + i) = lo;
}

// ---------------- MFMA GEMM (pre-split bf16 A and B) ----------------
// C_bf16[N][256] = (Ah+Al)[N][K] @ (Bh+Bl)^T[256][K], 3-term split.
// 128x64 tile, 4 waves, 16x16x32 bf16 MFMA.
#define LDT 40  // padded LDS stride (bf16 elems)
__global__ __launch_bounds__(256) void gemm2_k(const ushort_t* __restrict__ Ahg,
                                               const ushort_t* __restrict__ Alg,
                                               const ushort_t* __restrict__ Bh,
                                               const ushort_t* __restrict__ Bl,
                                               ushort_t* __restrict__ C,
                                               int N, int K) {
  __shared__ ushort_t Ahs[128 * LDT];
  __shared__ ushort_t Als[128 * LDT];
  __shared__ ushort_t Bhs[64 * LDT];
  __shared__ ushort_t Bls[64 * LDT];
  int t = threadIdx.x;
  int w = t >> 6, l = t & 63;
  long row0 = (long)blockIdx.x * 128;
  int col0 = blockIdx.y * 64;
  int fr = l & 15;
  int ko = (l >> 4) * 8;
  int ar = t >> 1;          // A staging: row 0..127
  int ak = (t & 1) * 16;    // A staging: k 0 or 16 (two uint4 each)
  int bc = t >> 2;          // B staging: col 0..63
  int bk = (t & 3) * 8;     // B staging: k 0,8,16,24
  f32x4 acc[2][4] = {};

  for (int k0 = 0; k0 < K; k0 += 32) {
    const ushort_t* ap = Ahg + (row0 + ar) * K + k0 + ak;
    const ushort_t* lp = Alg + (row0 + ar) * K + k0 + ak;
    uint4 ah0 = *(const uint4*)ap;
    uint4 ah1 = *(const uint4*)(ap + 8);
    uint4 al0 = *(const uint4*)lp;
    uint4 al1 = *(const uint4*)(lp + 8);
    uint4 bh = *(const uint4*)(Bh + (long)(col0 + bc) * K + k0 + bk);
    uint4 bl = *(const uint4*)(Bl + (long)(col0 + bc) * K + k0 + bk);
    __syncthreads();
    *(uint4*)&Ahs[ar * LDT + ak] = ah0;
    *(uint4*)&Ahs[ar * LDT + ak + 8] = ah1;
    *(uint4*)&Als[ar * LDT + ak] = al0;
    *(uint4*)&Als[ar * LDT + ak + 8] = al1;
    *(uint4*)&Bhs[bc * LDT + bk] = bh;
    *(uint4*)&Bls[bc * LDT + bk] = bl;
    __syncthreads();
    short8 fah[2], fal[2], fbh[4], fbl[4];
    #pragma unroll
    for (int m = 0; m < 2; ++m) {
      fah[m] = *(const short8*)&Ahs[(w * 32 + m * 16 + fr) * LDT + ko];
      fal[m] = *(const short8*)&Als[(w * 32 + m * 16 + fr) * LDT + ko];
    }
    #pragma unroll
    for (int n = 0; n < 4; ++n) {
      fbh[n] = *(const short8*)&Bhs[(n * 16 + fr) * LDT + ko];
      fbl[n] = *(const short8*)&Bls[(n * 16 + fr) * LDT + ko];
    }
    #pragma unroll
    for (int m = 0; m < 2; ++m) {
      #pragma unroll
      for (int n = 0; n < 4; ++n) {
        acc[m][n] = __builtin_amdgcn_mfma_f32_16x16x32_bf16(fah[m], fbh[n], acc[m][n], 0, 0, 0);
        acc[m][n] = __builtin_amdgcn_mfma_f32_16x16x32_bf16(fal[m], fbh[n], acc[m][n], 0, 0, 0);
        acc[m][n] = __builtin_amdgcn_mfma_f32_16x16x32_bf16(fah[m], fbl[n], acc[m][n], 0, 0, 0);
      }
    }
  }
  int crow = (l >> 4) * 4;
  #pragma unroll
  for (int m = 0; m < 2; ++m) {
    #pragma unroll
    for (int n = 0; n < 4; ++n) {
      #pragma unroll
      for (int r = 0; r < 4; ++r) {
        long row = row0 + w * 32 + m * 16 + crow + r;
        int col = col0 + n * 16 + fr;
        C[row * 256 + col] = f2bf(acc[m][n][r]);
      }
    }
  }
}

// ---------------- el/er from bf16 h ----------------
__global__ void eler_k(const ushort_t* __restrict__ h, const float* __restrict__ al,
                       const float* __restrict__ ar, float* __restrict__ el,
                       float* __restrict__ er, int N) {
  int i = blockIdx.x * blockDim.x + threadIdx.x;
  if (i >= N * 8) return;
  int n = i >> 3, hh = i & 7;
  const ushort_t* hp = h + (long)n * 256 + hh * 32;
  const float* alp = al + hh * 32;
  const float* arp = ar + hh * 32;
  float sl = 0.f, sr = 0.f;
  #pragma unroll
  for (int q = 0; q < 4; ++q) {
    uint4 v = *(const uint4*)(hp + q * 8);
    unsigned vv[4] = {v.x, v.y, v.z, v.w};
    #pragma unroll
    for (int j = 0; j < 4; ++j) {
      float f0 = bf2f((unsigned short)(vv[j] & 0xffff));
      float f1 = bf2f((unsigned short)(vv[j] >> 16));
      int d = q * 8 + j * 2;
      sl += f0 * alp[d] + f1 * alp[d + 1];
      sr += f0 * arp[d] + f1 * arp[d + 1];
    }
  }
  el[i] = sl;
  er[i] = sr;
}

// ---------------- agg: bf16 gather, wave-per-node; epilogue f32 or hi/lo split ----------------
template <int SPLIT>
__global__ __launch_bounds__(256) void agg_t_k(const ushort_t* __restrict__ hb,
                                               const float* __restrict__ el,
                                               const float* __restrict__ er,
                                               const int* __restrict__ ptr,
                                               const int* __restrict__ eidx,
                                               const int* __restrict__ src,
                                               float* __restrict__ outf,
                                               ushort_t* __restrict__ oh,
                                               ushort_t* __restrict__ ol, int N) {
  int wid = threadIdx.x >> 6;
  int l = threadIdx.x & 63;
  int n = blockIdx.x * 4 + wid;
  if (n >= N) return;
  int beg = ptr[n];
  int deg = ptr[n + 1] - beg;
  long obase = (long)n * 256 + l * 4;
  float4 acc = make_float4(0.f, 0.f, 0.f, 0.f);
  if (deg > 0) {
    int hh = l & 7;
    int eo = l >> 3;
    int hg = l >> 3;
    float erv = er[(long)n * 8 + hh];
    if (deg <= 64) {
      int sid = (l < deg) ? src[eidx[beg + l]] : 0;
      int npass = (deg + 7) >> 3;
      float v[8];
      float m = -1e30f;
      #pragma unroll
      for (int p = 0; p < 8; ++p) {
        if (p < npass) {
          int e = p * 8 + eo;
          int s = __shfl(sid, e);
          float vv = -1e30f;
          if (e < deg) {
            vv = el[(long)s * 8 + hh] + erv;
            vv = vv > 0.f ? vv : LEAKY * vv;
          }
          v[p] = vv;
          m = fmaxf(m, vv);
        }
      }
      m = fmaxf(m, __shfl_xor(m, 8));
      m = fmaxf(m, __shfl_xor(m, 16));
      m = fmaxf(m, __shfl_xor(m, 32));
      float ssum = 0.f;
      #pragma unroll
      for (int p = 0; p < 8; ++p) {
        if (p < npass) {
          float ex = (p * 8 + eo < deg) ? __expf(v[p] - m) : 0.f;
          v[p] = ex;
          ssum += ex;
        }
      }
      ssum += __shfl_xor(ssum, 8);
      ssum += __shfl_xor(ssum, 16);
      ssum += __shfl_xor(ssum, 32);
      float inv = 1.0f / ssum;
      #pragma unroll
      for (int p = 0; p < 8; ++p) {
        if (p < npass) {
          v[p] *= inv;
          #pragma unroll
          for (int e2 = 0; e2 < 8; ++e2) {
            int e = p * 8 + e2;
            if (e < deg) {
              float a = __shfl(v[p], (e2 << 3) | hg);
              int s = __shfl(sid, e);
              const ushort4 hv = *(const ushort4*)(hb + (long)s * 256 + l * 4);
              acc.x += a * bf2f(hv.x);
              acc.y += a * bf2f(hv.y);
              acc.z += a * bf2f(hv.z);
              acc.w += a * bf2f(hv.w);
            }
          }
        }
      }
    } else {
      float m = -1e30f;
      for (int base = 0; base < deg; base += 8) {
        int e = base + eo;
        float vv = -1e30f;
        if (e < deg) {
          int s = src[eidx[beg + e]];
          vv = el[(long)s * 8 + hh] + erv;
          vv = vv > 0.f ? vv : LEAKY * vv;
        }
        m = fmaxf(m, vv);
      }
      m = fmaxf(m, __shfl_xor(m, 8));
      m = fmaxf(m, __shfl_xor(m, 16));
      m = fmaxf(m, __shfl_xor(m, 32));
      float ssum = 0.f;
      for (int base = 0; base < deg; base += 8) {
        int e = base + eo;
        if (e < deg) {
          int s = src[eidx[beg + e]];
          float vv = el[(long)s * 8 + hh] + erv;
          vv = vv > 0.f ? vv : LEAKY * vv;
          ssum += __expf(vv - m);
        }
      }
      ssum += __shfl_xor(ssum, 8);
      ssum += __shfl_xor(ssum, 16);
      ssum += __shfl_xor(ssum, 32);
      float inv = 1.0f / ssum;
      for (int base = 0; base < deg; base += 8) {
        int e = base + eo;
        float a_me = 0.f;
        int s_me = 0;
        if (e < deg) {
          s_me = src[eidx[beg + e]];
          float vv = el[(long)s_me * 8 + hh] + erv;
          vv = vv > 0.f ? vv : LEAKY * vv;
          a_me = __expf(vv - m) * inv;
        }
        #pragma unroll
        for (int e2 = 0; e2 < 8; ++e2) {
          int e3 = base + e2;
          if (e3 < deg) {
            int srcl = (e2 << 3) | hg;
            float a = __shfl(a_me, srcl);
            int s = __shfl(s_me, srcl);
            const ushort4 hv = *(const ushort4*)(hb + (long)s * 256 + l * 4);
            acc.x += a * bf2f(hv.x);
            acc.y += a * bf2f(hv.y);
            acc.z += a * bf2f(hv.z);
            acc.w += a * bf2f(hv.w);
          }
        }
      }
    }
  }
  if (SPLIT) {
    unsigned short hx = f2bf(acc.x), hy = f2bf(acc.y), hz = f2bf(acc.z), hw = f2bf(acc.w);
    ushort4 hi = make_ushort4(hx, hy, hz, hw);
    ushort4 lo = make_ushort4(f2bf(acc.x - bf2f(hx)), f2bf(acc.y - bf2f(hy)),
                              f2bf(acc.z - bf2f(hz)), f2bf(acc.w - bf2f(hw)));
    *(ushort4*)(oh + obase) = hi;
    *(ushort4*)(ol + obase) = lo;
  } else {
    *(float4*)(outf + obase) = acc;
  }
}

// ---------------- per-graph mean pooling ----------------
__device__ __forceinline__ int lower_bound_i(const int* a, int n, int key) {
  int lo = 0, hi = n;
  while (lo < hi) {
    int mid = (lo + hi) >> 1;
    if (a[mid] < key) lo = mid + 1; else hi = mid;
  }
  return lo;
}

__global__ __launch_bounds__(256) void pool_k(const float* __restrict__ h,
                                              const int* __restrict__ gid,
                                              float* __restrict__ pooled, int N, int G) {
  int g = blockIdx.x;
  int t = threadIdx.x;
  __shared__ int s_lo, s_hi;
  if (t == 0) {
    s_lo = lower_bound_i(gid, N, g);
    s_hi = lower_bound_i(gid, N, g + 1);
  }
  __syncthreads();
  int lo = s_lo, hi = s_hi;
  float acc = 0.f;
  for (int n = lo; n < hi; ++n) acc += h[(long)n * 256 + t];
  float c = (float)(hi - lo);
  pooled[g * 256 + t] = acc / fmaxf(c, 1.f);
}

// ---------------- MLP ----------------
__global__ __launch_bounds__(256) void mlp_k(const float* __restrict__ pooled,
                                             const float* __restrict__ Wd1,
                                             const float* __restrict__ bd1,
                                             const float* __restrict__ Wd2,
                                             const float* __restrict__ bd2,
                                             float* __restrict__ outv, int G) {
  int g = blockIdx.x;
  int t = threadIdx.x;
  __shared__ float p_s[256];
  __shared__ float red[256];
  p_s[t] = pooled[g * 256 + t];
  __syncthreads();
  float acc0 = bd1[t], acc1 = bd1[t + 256];
  for (int k = 0; k < 256; ++k) {
    float pv = p_s[k];
    acc0 += pv * Wd1[k * 512 + t];
    acc1 += pv * Wd1[k * 512 + t + 256];
  }
  acc0 = fmaxf(acc0, 0.f);
  acc1 = fmaxf(acc1, 0.f);
  red[t] = acc0 * Wd2[t] + acc1 * Wd2[t + 256];
  __syncthreads();
  for (int off = 128; off > 0; off >>= 1) {
    if (t < off) red[t] += red[t + off];
    __syncthreads();
  }
  if (t == 0) outv[g] = red[0] + bd2[0];
}

extern "C" void kernel_launch(void* const* d_in, const int* in_sizes, int n_in,
                              void* d_out, int out_size, void* d_ws, size_t ws_size,
                              hipStream_t stream) {
  const float* X   = (const float*)d_in[0];
  const int*   src = (const int*)d_in[1];
  const int*   dst = (const int*)d_in[2];
  const int*   gid = (const int*)d_in[3];
  const float* W0  = (const float*)d_in[5];
  const float* al0 = (const float*)d_in[6];
  const float* ar0 = (const float*)d_in[7];
  const float* W1  = (const float*)d_in[8];
  const float* al1 = (const float*)d_in[9];
  const float* ar1 = (const float*)d_in[10];
  const float* Wd1 = (const float*)d_in[11];
  const float* bd1 = (const float*)d_in[12];
  const float* Wd2 = (const float*)d_in[13];
  const float* bd2 = (const float*)d_in[14];

  int E = in_sizes[1];
  int N = in_sizes[3];
  int G = out_size;

  // Region R1 (N*256 f32 = largest): hosts Xh/Xl (phase 1), then Ah/Al (phase 2),
  // then bAgg f32 (phase 3). Lifetimes are disjoint.
  char* w = (char*)d_ws;
  ushort_t* Xh   = (ushort_t*)w;                   // [N*128]
  ushort_t* Xl   = Xh + (size_t)N * 128;           // [N*128]
  ushort_t* Ah   = (ushort_t*)w;                   // [N*256]
  ushort_t* Al   = Ah + (size_t)N * 256;           // [N*256]
  float*    bAgg = (float*)w;                      // [N*256] f32
  char* p = w + (size_t)N * 256 * 4;
  ushort_t* hb   = (ushort_t*)p; p += (size_t)N * 256 * 2;   // [N,256] bf16 h
  float*    el   = (float*)p;    p += (size_t)N * 8 * 4;
  float*    er   = (float*)p;    p += (size_t)N * 8 * 4;
  float*    pooled = (float*)p;  p += (size_t)G * 256 * 4;
  ushort_t* W0h  = (ushort_t*)p; p += (size_t)256 * 128 * 2;
  ushort_t* W0l  = (ushort_t*)p; p += (size_t)256 * 128 * 2;
  ushort_t* W1h  = (ushort_t*)p; p += (size_t)256 * 256 * 2;
  ushort_t* W1l  = (ushort_t*)p; p += (size_t)256 * 256 * 2;
  int*      ptr  = (int*)p;      p += (size_t)(N + 1) * 4;
  int*      cnt  = (int*)p;      p += (size_t)N * 4;
  int*      eidx = (int*)p;      p += (size_t)E * 4;
  int*      bsum = (int*)p;

  int nb = (N + 1023) / 1024;

  // CSR build over dst
  hipMemsetAsync(cnt, 0, (size_t)N * 4, stream);
  count_k<<<(E + 255) / 256, 256, 0, stream>>>(dst, cnt, E);
  scan1_k<<<nb, 1024, 0, stream>>>(cnt, ptr, bsum, N);
  scan2_k<<<1, 64, 0, stream>>>(bsum, nb);
  scan3_k<<<nb, 1024, 0, stream>>>(ptr, bsum, N, E);
  hipMemsetAsync(cnt, 0, (size_t)N * 4, stream);
  fill_k<<<(E + 255) / 256, 256, 0, stream>>>(dst, ptr, cnt, eidx, E);

  // weight + input splits
  wsplit_k<<<(256 * 128 + 255) / 256, 256, 0, stream>>>(W0, W0h, W0l, 128);
  wsplit_k<<<(256 * 256 + 255) / 256, 256, 0, stream>>>(W1, W1h, W1l, 256);
  asplit_k<<<(int)(((long)N * 128 / 4 + 255) / 256), 256, 0, stream>>>(X, Xh, Xl, (long)N * 128);

  dim3 gg(N / 128, 4);
  // layer 0
  gemm2_k<<<gg, 256, 0, stream>>>(Xh, Xl, W0h, W0l, hb, N, 128);
  eler_k<<<(N * 8 + 255) / 256, 256, 0, stream>>>(hb, al0, ar0, el, er, N);
  agg_t_k<1><<<(N + 3) / 4, 256, 0, stream>>>(hb, el, er, ptr, eidx, src, (float*)nullptr, Ah, Al, N);
  // layer 1
  gemm2_k<<<gg, 256, 0, stream>>>(Ah, Al, W1h, W1l, hb, N, 256);
  eler_k<<<(N * 8 + 255) / 256, 256, 0, stream>>>(hb, al1, ar1, el, er, N);
  agg_t_k<0><<<(N + 3) / 4, 256, 0, stream>>>(hb, el, er, ptr, eidx, src, bAgg, (ushort_t*)nullptr, (ushort_t*)nullptr, N);
  // readout + MLP
  pool_k<<<G, 256, 0, stream>>>(bAgg, gid, pooled, N, G);
  mlp_k<<<G, 256, 0, stream>>>(pooled, Wd1, bd1, Wd2, bd2, (float*)d_out, G);
}

// Round 7
// 479.948 us; speedup vs baseline: 1.1454x; 1.1454x over previous
//
#include <hip/hip_runtime.h>

#define LEAKY 0.2f

typedef unsigned short ushort_t;
typedef __attribute__((ext_vector_type(8))) short short8;
typedef __attribute__((ext_vector_type(4))) float f32x4;

__device__ __forceinline__ unsigned short f2bf(float f) {
  unsigned u = __float_as_uint(f);
  unsigned r = (u + 0x7fff + ((u >> 16) & 1)) >> 16;  // RNE
  return (unsigned short)r;
}
__device__ __forceinline__ float bf2f(unsigned short u) {
  return __uint_as_float(((unsigned)u) << 16);
}

// ---------------- CSR build ----------------
__global__ void count_k(const int* __restrict__ dst, int* __restrict__ cnt, int E) {
  int i = blockIdx.x * blockDim.x + threadIdx.x;
  if (i < E) atomicAdd(&cnt[dst[i]], 1);
}

// hierarchical scan; also zeroes cnt for reuse as fill cursor
__global__ __launch_bounds__(1024) void scan1_k(int* __restrict__ cnt,
                                                int* __restrict__ ptr,
                                                int* __restrict__ bsum, int N) {
  int t = threadIdx.x;
  int i = blockIdx.x * 1024 + t;
  int v = (i < N) ? cnt[i] : 0;
  if (i < N) cnt[i] = 0;
  int lane = t & 63, w = t >> 6;
  int x = v;
  #pragma unroll
  for (int off = 1; off < 64; off <<= 1) {
    int y = __shfl_up(x, off, 64);
    if (lane >= off) x += y;
  }
  __shared__ int wsum[16];
  if (lane == 63) wsum[w] = x;
  __syncthreads();
  if (t < 16) {
    int s = wsum[t];
    #pragma unroll
    for (int off = 1; off < 16; off <<= 1) {
      int y = __shfl_up(s, off, 16);
      if (t >= off) s += y;
    }
    wsum[t] = s;
  }
  __syncthreads();
  int woff = (w > 0) ? wsum[w - 1] : 0;
  int incl = x + woff;
  if (i < N) ptr[i] = incl - v;
  if (t == 1023) bsum[blockIdx.x] = incl;
}

__global__ void scan2_k(int* __restrict__ bsum, int nb) {
  int t = threadIdx.x;
  int v = (t < nb) ? bsum[t] : 0;
  int x = v;
  #pragma unroll
  for (int off = 1; off < 64; off <<= 1) {
    int y = __shfl_up(x, off, 64);
    if (t >= off) x += y;
  }
  if (t < nb) bsum[t] = x - v;
}

__global__ __launch_bounds__(1024) void scan3_k(int* __restrict__ ptr,
                                                const int* __restrict__ bsum,
                                                int N, int E) {
  int i = blockIdx.x * 1024 + threadIdx.x;
  if (i < N) ptr[i] += bsum[blockIdx.x];
  if (i == 0) ptr[N] = E;
}

// stores SRC VALUES directly (adjacency), not edge indices
__global__ void fill_k(const int* __restrict__ dst, const int* __restrict__ src,
                       const int* __restrict__ ptr, int* __restrict__ cur,
                       int* __restrict__ adj, int E) {
  int i = blockIdx.x * blockDim.x + threadIdx.x;
  if (i < E) {
    int d = dst[i];
    int p = atomicAdd(&cur[d], 1);
    adj[ptr[d] + p] = src[i];
  }
}

// ---------------- W split+transpose: W[K][256] -> Wh/Wl[256][K] bf16 ----------------
__global__ void wsplit_k(const float* __restrict__ W, ushort_t* __restrict__ Wh,
                         ushort_t* __restrict__ Wl, int K) {
  int i = blockIdx.x * 256 + threadIdx.x;
  if (i >= 256 * K) return;
  int k = i % K, c = i / K;
  float x = W[(long)k * 256 + c];
  unsigned short hi = f2bf(x);
  Wh[i] = hi;
  Wl[i] = f2bf(x - bf2f(hi));
}

// ---------------- A split: A_f32[N*K] -> Ah/Al bf16 ----------------
__global__ __launch_bounds__(256) void asplit_k(const float* __restrict__ A,
                                                ushort_t* __restrict__ Ah,
                                                ushort_t* __restrict__ Al, long total) {
  long i = ((long)blockIdx.x * 256 + threadIdx.x) * 4;
  if (i >= total) return;
  float4 v = *(const float4*)(A + i);
  unsigned short h0 = f2bf(v.x), h1 = f2bf(v.y), h2 = f2bf(v.z), h3 = f2bf(v.w);
  ushort4 hi = make_ushort4(h0, h1, h2, h3);
  ushort4 lo = make_ushort4(f2bf(v.x - bf2f(h0)), f2bf(v.y - bf2f(h1)),
                            f2bf(v.z - bf2f(h2)), f2bf(v.w - bf2f(h3)));
  *(ushort4*)(Ah + i) = hi;
  *(ushort4*)(Al + i) = lo;
}

// ---------------- MFMA GEMM + fused el/er epilogue ----------------
// C_bf16[N][256] = (Ah+Al)[N][K] @ (Bh+Bl)^T[256][K], 3-term split.
// Col-block by covers heads {2by, 2by+1}; el/er computed from f32 acc.
#define LDT 40
__global__ __launch_bounds__(256) void gemm2_k(const ushort_t* __restrict__ Ahg,
                                               const ushort_t* __restrict__ Alg,
                                               const ushort_t* __restrict__ Bh,
                                               const ushort_t* __restrict__ Bl,
                                               const float* __restrict__ alv,
                                               const float* __restrict__ arv,
                                               ushort_t* __restrict__ C,
                                               float* __restrict__ el,
                                               float* __restrict__ er,
                                               int N, int K) {
  __shared__ ushort_t Ahs[128 * LDT];
  __shared__ ushort_t Als[128 * LDT];
  __shared__ ushort_t Bhs[64 * LDT];
  __shared__ ushort_t Bls[64 * LDT];
  int t = threadIdx.x;
  int w = t >> 6, l = t & 63;
  long row0 = (long)blockIdx.x * 128;
  int by = blockIdx.y;
  int col0 = by * 64;
  int fr = l & 15;
  int ko = (l >> 4) * 8;
  int ar = t >> 1;
  int ak = (t & 1) * 16;
  int bc = t >> 2;
  int bk = (t & 3) * 8;
  f32x4 acc[2][4] = {};

  for (int k0 = 0; k0 < K; k0 += 32) {
    const ushort_t* ap = Ahg + (row0 + ar) * K + k0 + ak;
    const ushort_t* lp = Alg + (row0 + ar) * K + k0 + ak;
    uint4 ah0 = *(const uint4*)ap;
    uint4 ah1 = *(const uint4*)(ap + 8);
    uint4 al0 = *(const uint4*)lp;
    uint4 al1 = *(const uint4*)(lp + 8);
    uint4 bh = *(const uint4*)(Bh + (long)(col0 + bc) * K + k0 + bk);
    uint4 bl = *(const uint4*)(Bl + (long)(col0 + bc) * K + k0 + bk);
    __syncthreads();
    *(uint4*)&Ahs[ar * LDT + ak] = ah0;
    *(uint4*)&Ahs[ar * LDT + ak + 8] = ah1;
    *(uint4*)&Als[ar * LDT + ak] = al0;
    *(uint4*)&Als[ar * LDT + ak + 8] = al1;
    *(uint4*)&Bhs[bc * LDT + bk] = bh;
    *(uint4*)&Bls[bc * LDT + bk] = bl;
    __syncthreads();
    short8 fah[2], fal[2], fbh[4], fbl[4];
    #pragma unroll
    for (int m = 0; m < 2; ++m) {
      fah[m] = *(const short8*)&Ahs[(w * 32 + m * 16 + fr) * LDT + ko];
      fal[m] = *(const short8*)&Als[(w * 32 + m * 16 + fr) * LDT + ko];
    }
    #pragma unroll
    for (int n = 0; n < 4; ++n) {
      fbh[n] = *(const short8*)&Bhs[(n * 16 + fr) * LDT + ko];
      fbl[n] = *(const short8*)&Bls[(n * 16 + fr) * LDT + ko];
    }
    #pragma unroll
    for (int m = 0; m < 2; ++m) {
      #pragma unroll
      for (int n = 0; n < 4; ++n) {
        acc[m][n] = __builtin_amdgcn_mfma_f32_16x16x32_bf16(fah[m], fbh[n], acc[m][n], 0, 0, 0);
        acc[m][n] = __builtin_amdgcn_mfma_f32_16x16x32_bf16(fal[m], fbh[n], acc[m][n], 0, 0, 0);
        acc[m][n] = __builtin_amdgcn_mfma_f32_16x16x32_bf16(fah[m], fbl[n], acc[m][n], 0, 0, 0);
      }
    }
  }
  int crow = (l >> 4) * 4;
  // attn vector scalars for this col-block's two heads
  float al0a = alv[(2 * by + 0) * 32 + fr], al0b = alv[(2 * by + 0) * 32 + 16 + fr];
  float al1a = alv[(2 * by + 1) * 32 + fr], al1b = alv[(2 * by + 1) * 32 + 16 + fr];
  float ar0a = arv[(2 * by + 0) * 32 + fr], ar0b = arv[(2 * by + 0) * 32 + 16 + fr];
  float ar1a = arv[(2 * by + 1) * 32 + fr], ar1b = arv[(2 * by + 1) * 32 + 16 + fr];
  #pragma unroll
  for (int m = 0; m < 2; ++m) {
    #pragma unroll
    for (int r = 0; r < 4; ++r) {
      long row = row0 + w * 32 + m * 16 + crow + r;
      // C writes
      #pragma unroll
      for (int n = 0; n < 4; ++n)
        C[row * 256 + col0 + n * 16 + fr] = f2bf(acc[m][n][r]);
      // fused el/er: reduce over the 16 fr-lanes (full 64 cols of this row)
      float pel0 = acc[m][0][r] * al0a + acc[m][1][r] * al0b;
      float pel1 = acc[m][2][r] * al1a + acc[m][3][r] * al1b;
      float per0 = acc[m][0][r] * ar0a + acc[m][1][r] * ar0b;
      float per1 = acc[m][2][r] * ar1a + acc[m][3][r] * ar1b;
      #pragma unroll
      for (int s = 1; s < 16; s <<= 1) {
        pel0 += __shfl_xor(pel0, s);
        pel1 += __shfl_xor(pel1, s);
        per0 += __shfl_xor(per0, s);
        per1 += __shfl_xor(per1, s);
      }
      if (fr == 0) {
        el[row * 8 + 2 * by] = pel0;
        el[row * 8 + 2 * by + 1] = pel1;
        er[row * 8 + 2 * by] = per0;
        er[row * 8 + 2 * by + 1] = per1;
      }
    }
  }
}

// ---------------- agg: bf16 gather, wave-per-node; adj holds src values ----------------
template <int SPLIT>
__global__ __launch_bounds__(256) void agg_t_k(const ushort_t* __restrict__ hb,
                                               const float* __restrict__ el,
                                               const float* __restrict__ er,
                                               const int* __restrict__ ptr,
                                               const int* __restrict__ adj,
                                               float* __restrict__ outf,
                                               ushort_t* __restrict__ oh,
                                               ushort_t* __restrict__ ol, int N) {
  int wid = threadIdx.x >> 6;
  int l = threadIdx.x & 63;
  int n = blockIdx.x * 4 + wid;
  if (n >= N) return;
  int beg = ptr[n];
  int deg = ptr[n + 1] - beg;
  long obase = (long)n * 256 + l * 4;
  float4 acc = make_float4(0.f, 0.f, 0.f, 0.f);
  if (deg > 0) {
    int hh = l & 7;
    int eo = l >> 3;
    int hg = l >> 3;
    float erv = er[(long)n * 8 + hh];
    if (deg <= 64) {
      int sid = (l < deg) ? adj[beg + l] : 0;
      int npass = (deg + 7) >> 3;
      float v[8];
      float m = -1e30f;
      #pragma unroll
      for (int p = 0; p < 8; ++p) {
        if (p < npass) {
          int e = p * 8 + eo;
          int s = __shfl(sid, e);
          float vv = -1e30f;
          if (e < deg) {
            vv = el[(long)s * 8 + hh] + erv;
            vv = vv > 0.f ? vv : LEAKY * vv;
          }
          v[p] = vv;
          m = fmaxf(m, vv);
        }
      }
      m = fmaxf(m, __shfl_xor(m, 8));
      m = fmaxf(m, __shfl_xor(m, 16));
      m = fmaxf(m, __shfl_xor(m, 32));
      float ssum = 0.f;
      #pragma unroll
      for (int p = 0; p < 8; ++p) {
        if (p < npass) {
          float ex = (p * 8 + eo < deg) ? __expf(v[p] - m) : 0.f;
          v[p] = ex;
          ssum += ex;
        }
      }
      ssum += __shfl_xor(ssum, 8);
      ssum += __shfl_xor(ssum, 16);
      ssum += __shfl_xor(ssum, 32);
      float inv = 1.0f / ssum;
      #pragma unroll
      for (int p = 0; p < 8; ++p) {
        if (p < npass) {
          v[p] *= inv;
          #pragma unroll
          for (int e2 = 0; e2 < 8; ++e2) {
            int e = p * 8 + e2;
            if (e < deg) {
              float a = __shfl(v[p], (e2 << 3) | hg);
              int s = __shfl(sid, e);
              const ushort4 hv = *(const ushort4*)(hb + (long)s * 256 + l * 4);
              acc.x += a * bf2f(hv.x);
              acc.y += a * bf2f(hv.y);
              acc.z += a * bf2f(hv.z);
              acc.w += a * bf2f(hv.w);
            }
          }
        }
      }
    } else {
      float m = -1e30f;
      for (int base = 0; base < deg; base += 8) {
        int e = base + eo;
        float vv = -1e30f;
        if (e < deg) {
          int s = adj[beg + e];
          vv = el[(long)s * 8 + hh] + erv;
          vv = vv > 0.f ? vv : LEAKY * vv;
        }
        m = fmaxf(m, vv);
      }
      m = fmaxf(m, __shfl_xor(m, 8));
      m = fmaxf(m, __shfl_xor(m, 16));
      m = fmaxf(m, __shfl_xor(m, 32));
      float ssum = 0.f;
      for (int base = 0; base < deg; base += 8) {
        int e = base + eo;
        if (e < deg) {
          int s = adj[beg + e];
          float vv = el[(long)s * 8 + hh] + erv;
          vv = vv > 0.f ? vv : LEAKY * vv;
          ssum += __expf(vv - m);
        }
      }
      ssum += __shfl_xor(ssum, 8);
      ssum += __shfl_xor(ssum, 16);
      ssum += __shfl_xor(ssum, 32);
      float inv = 1.0f / ssum;
      for (int base = 0; base < deg; base += 8) {
        int e = base + eo;
        float a_me = 0.f;
        int s_me = 0;
        if (e < deg) {
          s_me = adj[beg + e];
          float vv = el[(long)s_me * 8 + hh] + erv;
          vv = vv > 0.f ? vv : LEAKY * vv;
          a_me = __expf(vv - m) * inv;
        }
        #pragma unroll
        for (int e2 = 0; e2 < 8; ++e2) {
          int e3 = base + e2;
          if (e3 < deg) {
            int srcl = (e2 << 3) | hg;
            float a = __shfl(a_me, srcl);
            int s = __shfl(s_me, srcl);
            const ushort4 hv = *(const ushort4*)(hb + (long)s * 256 + l * 4);
            acc.x += a * bf2f(hv.x);
            acc.y += a * bf2f(hv.y);
            acc.z += a * bf2f(hv.z);
            acc.w += a * bf2f(hv.w);
          }
        }
      }
    }
  }
  if (SPLIT) {
    unsigned short hx = f2bf(acc.x), hy = f2bf(acc.y), hz = f2bf(acc.z), hw = f2bf(acc.w);
    ushort4 hi = make_ushort4(hx, hy, hz, hw);
    ushort4 lo = make_ushort4(f2bf(acc.x - bf2f(hx)), f2bf(acc.y - bf2f(hy)),
                              f2bf(acc.z - bf2f(hz)), f2bf(acc.w - bf2f(hw)));
    *(ushort4*)(oh + obase) = hi;
    *(ushort4*)(ol + obase) = lo;
  } else {
    *(float4*)(outf + obase) = acc;
  }
}

// ---------------- fused pool + MLP ----------------
__device__ __forceinline__ int lower_bound_i(const int* a, int n, int key) {
  int lo = 0, hi = n;
  while (lo < hi) {
    int mid = (lo + hi) >> 1;
    if (a[mid] < key) lo = mid + 1; else hi = mid;
  }
  return lo;
}

__global__ __launch_bounds__(256) void poolmlp_k(const float* __restrict__ h,
                                                 const int* __restrict__ gid,
                                                 const float* __restrict__ Wd1,
                                                 const float* __restrict__ bd1,
                                                 const float* __restrict__ Wd2,
                                                 const float* __restrict__ bd2,
                                                 float* __restrict__ outv, int N, int G) {
  int g = blockIdx.x;
  int t = threadIdx.x;
  __shared__ int s_lo, s_hi;
  if (t == 0) {
    s_lo = lower_bound_i(gid, N, g);
    s_hi = lower_bound_i(gid, N, g + 1);
  }
  __syncthreads();
  int lo = s_lo, hi = s_hi;
  float acc = 0.f;
  for (int n = lo; n < hi; ++n) acc += h[(long)n * 256 + t];
  float c = (float)(hi - lo);
  __shared__ float p_s[256];
  __shared__ float red[256];
  p_s[t] = acc / fmaxf(c, 1.f);
  __syncthreads();
  float acc0 = bd1[t], acc1 = bd1[t + 256];
  for (int k = 0; k < 256; ++k) {
    float pv = p_s[k];
    acc0 += pv * Wd1[k * 512 + t];
    acc1 += pv * Wd1[k * 512 + t + 256];
  }
  acc0 = fmaxf(acc0, 0.f);
  acc1 = fmaxf(acc1, 0.f);
  red[t] = acc0 * Wd2[t] + acc1 * Wd2[t + 256];
  __syncthreads();
  for (int off = 128; off > 0; off >>= 1) {
    if (t < off) red[t] += red[t + off];
    __syncthreads();
  }
  if (t == 0) outv[g] = red[0] + bd2[0];
}

extern "C" void kernel_launch(void* const* d_in, const int* in_sizes, int n_in,
                              void* d_out, int out_size, void* d_ws, size_t ws_size,
                              hipStream_t stream) {
  const float* X   = (const float*)d_in[0];
  const int*   src = (const int*)d_in[1];
  const int*   dst = (const int*)d_in[2];
  const int*   gid = (const int*)d_in[3];
  const float* W0  = (const float*)d_in[5];
  const float* al0 = (const float*)d_in[6];
  const float* ar0 = (const float*)d_in[7];
  const float* W1  = (const float*)d_in[8];
  const float* al1 = (const float*)d_in[9];
  const float* ar1 = (const float*)d_in[10];
  const float* Wd1 = (const float*)d_in[11];
  const float* bd1 = (const float*)d_in[12];
  const float* Wd2 = (const float*)d_in[13];
  const float* bd2 = (const float*)d_in[14];

  int E = in_sizes[1];
  int N = in_sizes[3];
  int G = out_size;

  // Region R1: Xh/Xl (phase 1) -> Ah/Al (phase 2) -> bAgg f32 (phase 3); disjoint lifetimes.
  char* w = (char*)d_ws;
  ushort_t* Xh   = (ushort_t*)w;                   // [N*128]
  ushort_t* Xl   = Xh + (size_t)N * 128;           // [N*128]
  ushort_t* Ah   = (ushort_t*)w;                   // [N*256]
  ushort_t* Al   = Ah + (size_t)N * 256;           // [N*256]
  float*    bAgg = (float*)w;                      // [N*256] f32
  char* p = w + (size_t)N * 256 * 4;
  ushort_t* hb   = (ushort_t*)p; p += (size_t)N * 256 * 2;   // [N,256] bf16 h
  float*    el   = (float*)p;    p += (size_t)N * 8 * 4;
  float*    er   = (float*)p;    p += (size_t)N * 8 * 4;
  ushort_t* W0h  = (ushort_t*)p; p += (size_t)256 * 128 * 2;
  ushort_t* W0l  = (ushort_t*)p; p += (size_t)256 * 128 * 2;
  ushort_t* W1h  = (ushort_t*)p; p += (size_t)256 * 256 * 2;
  ushort_t* W1l  = (ushort_t*)p; p += (size_t)256 * 256 * 2;
  int*      ptr  = (int*)p;      p += (size_t)(N + 1) * 4;
  int*      cnt  = (int*)p;      p += (size_t)N * 4;
  int*      adj  = (int*)p;      p += (size_t)E * 4;
  int*      bsum = (int*)p;

  int nb = (N + 1023) / 1024;

  // CSR build over dst (adj stores src values)
  hipMemsetAsync(cnt, 0, (size_t)N * 4, stream);
  count_k<<<(E + 255) / 256, 256, 0, stream>>>(dst, cnt, E);
  scan1_k<<<nb, 1024, 0, stream>>>(cnt, ptr, bsum, N);  // also zeroes cnt
  scan2_k<<<1, 64, 0, stream>>>(bsum, nb);
  scan3_k<<<nb, 1024, 0, stream>>>(ptr, bsum, N, E);
  fill_k<<<(E + 255) / 256, 256, 0, stream>>>(dst, src, ptr, cnt, adj, E);

  // weight + input splits
  wsplit_k<<<(256 * 128 + 255) / 256, 256, 0, stream>>>(W0, W0h, W0l, 128);
  wsplit_k<<<(256 * 256 + 255) / 256, 256, 0, stream>>>(W1, W1h, W1l, 256);
  asplit_k<<<(int)(((long)N * 128 / 4 + 255) / 256), 256, 0, stream>>>(X, Xh, Xl, (long)N * 128);

  dim3 gg(N / 128, 4);
  // layer 0 (gemm writes hb + el/er fused)
  gemm2_k<<<gg, 256, 0, stream>>>(Xh, Xl, W0h, W0l, al0, ar0, hb, el, er, N, 128);
  agg_t_k<1><<<(N + 3) / 4, 256, 0, stream>>>(hb, el, er, ptr, adj, (float*)nullptr, Ah, Al, N);
  // layer 1
  gemm2_k<<<gg, 256, 0, stream>>>(Ah, Al, W1h, W1l, al1, ar1, hb, el, er, N, 256);
  agg_t_k<0><<<(N + 3) / 4, 256, 0, stream>>>(hb, el, er, ptr, adj, bAgg, (ushort_t*)nullptr, (ushort_t*)nullptr, N);
  // readout + MLP (fused)
  poolmlp_k<<<G, 256, 0, stream>>>(bAgg, gid, Wd1, bd1, Wd2, bd2, (float*)d_out, N, G);
}

// Round 8
// 468.262 us; speedup vs baseline: 1.1740x; 1.0250x over previous
//
#include <hip/hip_runtime.h>

#define LEAKY 0.2f

typedef unsigned short ushort_t;
typedef __attribute__((ext_vector_type(8))) short short8;
typedef __attribute__((ext_vector_type(4))) float f32x4;

__device__ __forceinline__ unsigned short f2bf(float f) {
  unsigned u = __float_as_uint(f);
  unsigned r = (u + 0x7fff + ((u >> 16) & 1)) >> 16;  // RNE
  return (unsigned short)r;
}
__device__ __forceinline__ float bf2f(unsigned short u) {
  return __uint_as_float(((unsigned)u) << 16);
}

// ---------------- CSR build ----------------
__global__ void count_k(const int* __restrict__ dst, int* __restrict__ cnt, int E) {
  int i = blockIdx.x * blockDim.x + threadIdx.x;
  if (i < E) atomicAdd(&cnt[dst[i]], 1);
}

// hierarchical scan; also zeroes cnt for reuse as fill cursor
__global__ __launch_bounds__(1024) void scan1_k(int* __restrict__ cnt,
                                                int* __restrict__ ptr,
                                                int* __restrict__ bsum, int N) {
  int t = threadIdx.x;
  int i = blockIdx.x * 1024 + t;
  int v = (i < N) ? cnt[i] : 0;
  if (i < N) cnt[i] = 0;
  int lane = t & 63, w = t >> 6;
  int x = v;
  #pragma unroll
  for (int off = 1; off < 64; off <<= 1) {
    int y = __shfl_up(x, off, 64);
    if (lane >= off) x += y;
  }
  __shared__ int wsum[16];
  if (lane == 63) wsum[w] = x;
  __syncthreads();
  if (t < 16) {
    int s = wsum[t];
    #pragma unroll
    for (int off = 1; off < 16; off <<= 1) {
      int y = __shfl_up(s, off, 16);
      if (t >= off) s += y;
    }
    wsum[t] = s;
  }
  __syncthreads();
  int woff = (w > 0) ? wsum[w - 1] : 0;
  int incl = x + woff;
  if (i < N) ptr[i] = incl - v;
  if (t == 1023) bsum[blockIdx.x] = incl;
}

__global__ void scan2_k(int* __restrict__ bsum, int nb) {
  int t = threadIdx.x;
  int v = (t < nb) ? bsum[t] : 0;
  int x = v;
  #pragma unroll
  for (int off = 1; off < 64; off <<= 1) {
    int y = __shfl_up(x, off, 64);
    if (t >= off) x += y;
  }
  if (t < nb) bsum[t] = x - v;
}

__global__ __launch_bounds__(1024) void scan3_k(int* __restrict__ ptr,
                                                const int* __restrict__ bsum,
                                                int N, int E) {
  int i = blockIdx.x * 1024 + threadIdx.x;
  if (i < N) ptr[i] += bsum[blockIdx.x];
  if (i == 0) ptr[N] = E;
}

// stores SRC VALUES directly (adjacency), not edge indices
__global__ void fill_k(const int* __restrict__ dst, const int* __restrict__ src,
                       const int* __restrict__ ptr, int* __restrict__ cur,
                       int* __restrict__ adj, int E) {
  int i = blockIdx.x * blockDim.x + threadIdx.x;
  if (i < E) {
    int d = dst[i];
    int p = atomicAdd(&cur[d], 1);
    adj[ptr[d] + p] = src[i];
  }
}

// ---------------- W transpose to bf16 (hi only): W[K][256] -> Wh[256][K] ----------------
__global__ void whsplit_k(const float* __restrict__ W, ushort_t* __restrict__ Wh, int K) {
  int i = blockIdx.x * 256 + threadIdx.x;
  if (i >= 256 * K) return;
  int k = i % K, c = i / K;
  Wh[i] = f2bf(W[(long)k * 256 + c]);
}

// ---------------- A split: A_f32[N*K] -> Ah/Al bf16 ----------------
__global__ __launch_bounds__(256) void asplit_k(const float* __restrict__ A,
                                                ushort_t* __restrict__ Ah,
                                                ushort_t* __restrict__ Al, long total) {
  long i = ((long)blockIdx.x * 256 + threadIdx.x) * 4;
  if (i >= total) return;
  float4 v = *(const float4*)(A + i);
  unsigned short h0 = f2bf(v.x), h1 = f2bf(v.y), h2 = f2bf(v.z), h3 = f2bf(v.w);
  ushort4 hi = make_ushort4(h0, h1, h2, h3);
  ushort4 lo = make_ushort4(f2bf(v.x - bf2f(h0)), f2bf(v.y - bf2f(h1)),
                            f2bf(v.z - bf2f(h2)), f2bf(v.w - bf2f(h3)));
  *(ushort4*)(Ah + i) = hi;
  *(ushort4*)(Al + i) = lo;
}

// ---------------- MFMA GEMM (128x128 tile, 2-term A-split) + fused el/er ----------------
// C_bf16[N][256] = (Ah+Al)[N][K] @ Wh^T[256][K].
// Col-block by covers heads {4by..4by+3}; el/er computed from f32 acc.
#define LDT 40
__global__ __launch_bounds__(256) void gemm3_k(const ushort_t* __restrict__ Ahg,
                                               const ushort_t* __restrict__ Alg,
                                               const ushort_t* __restrict__ Bh,
                                               const float* __restrict__ alv,
                                               const float* __restrict__ arv,
                                               ushort_t* __restrict__ C,
                                               float* __restrict__ el,
                                               float* __restrict__ er,
                                               int N, int K) {
  __shared__ ushort_t Ahs[128 * LDT];
  __shared__ ushort_t Als[128 * LDT];
  __shared__ ushort_t Bhs[128 * LDT];
  int t = threadIdx.x;
  int w = t >> 6, l = t & 63;
  long row0 = (long)blockIdx.x * 128;
  int by = blockIdx.y;
  int col0 = by * 128;
  int fr = l & 15;
  int ko = (l >> 4) * 8;
  int ar = t >> 1;
  int ak = (t & 1) * 16;
  int bc = t >> 2;
  int bk = (t & 3) * 8;
  f32x4 acc[2][8] = {};

  for (int k0 = 0; k0 < K; k0 += 32) {
    const ushort_t* ap = Ahg + (row0 + ar) * K + k0 + ak;
    const ushort_t* lp = Alg + (row0 + ar) * K + k0 + ak;
    uint4 ah0 = *(const uint4*)ap;
    uint4 ah1 = *(const uint4*)(ap + 8);
    uint4 al0 = *(const uint4*)lp;
    uint4 al1 = *(const uint4*)(lp + 8);
    uint4 bh0 = *(const uint4*)(Bh + (long)(col0 + bc) * K + k0 + bk);
    uint4 bh1 = *(const uint4*)(Bh + (long)(col0 + bc + 64) * K + k0 + bk);
    __syncthreads();
    *(uint4*)&Ahs[ar * LDT + ak] = ah0;
    *(uint4*)&Ahs[ar * LDT + ak + 8] = ah1;
    *(uint4*)&Als[ar * LDT + ak] = al0;
    *(uint4*)&Als[ar * LDT + ak + 8] = al1;
    *(uint4*)&Bhs[bc * LDT + bk] = bh0;
    *(uint4*)&Bhs[(bc + 64) * LDT + bk] = bh1;
    __syncthreads();
    short8 fah[2], fal[2];
    #pragma unroll
    for (int m = 0; m < 2; ++m) {
      fah[m] = *(const short8*)&Ahs[(w * 32 + m * 16 + fr) * LDT + ko];
      fal[m] = *(const short8*)&Als[(w * 32 + m * 16 + fr) * LDT + ko];
    }
    #pragma unroll
    for (int n = 0; n < 8; ++n) {
      short8 fbh = *(const short8*)&Bhs[(n * 16 + fr) * LDT + ko];
      #pragma unroll
      for (int m = 0; m < 2; ++m) {
        acc[m][n] = __builtin_amdgcn_mfma_f32_16x16x32_bf16(fah[m], fbh, acc[m][n], 0, 0, 0);
        acc[m][n] = __builtin_amdgcn_mfma_f32_16x16x32_bf16(fal[m], fbh, acc[m][n], 0, 0, 0);
      }
    }
  }
  int crow = (l >> 4) * 4;
  // attn-vector scalars for this col-block's four heads
  float ala[4], alb[4], ara[4], arb[4];
  #pragma unroll
  for (int hd = 0; hd < 4; ++hd) {
    ala[hd] = alv[(4 * by + hd) * 32 + fr];
    alb[hd] = alv[(4 * by + hd) * 32 + 16 + fr];
    ara[hd] = arv[(4 * by + hd) * 32 + fr];
    arb[hd] = arv[(4 * by + hd) * 32 + 16 + fr];
  }
  #pragma unroll
  for (int m = 0; m < 2; ++m) {
    #pragma unroll
    for (int r = 0; r < 4; ++r) {
      long row = row0 + w * 32 + m * 16 + crow + r;
      #pragma unroll
      for (int n = 0; n < 8; ++n)
        C[row * 256 + col0 + n * 16 + fr] = f2bf(acc[m][n][r]);
      #pragma unroll
      for (int hd = 0; hd < 4; ++hd) {
        float pel = acc[m][2 * hd][r] * ala[hd] + acc[m][2 * hd + 1][r] * alb[hd];
        float per = acc[m][2 * hd][r] * ara[hd] + acc[m][2 * hd + 1][r] * arb[hd];
        #pragma unroll
        for (int s = 1; s < 16; s <<= 1) {
          pel += __shfl_xor(pel, s);
          per += __shfl_xor(per, s);
        }
        if (fr == 0) {
          el[row * 8 + 4 * by + hd] = pel;
          er[row * 8 + 4 * by + hd] = per;
        }
      }
    }
  }
}

// ---------------- agg: bf16 gather, wave-per-node; adj holds src values ----------------
template <int SPLIT>
__global__ __launch_bounds__(256) void agg_t_k(const ushort_t* __restrict__ hb,
                                               const float* __restrict__ el,
                                               const float* __restrict__ er,
                                               const int* __restrict__ ptr,
                                               const int* __restrict__ adj,
                                               float* __restrict__ outf,
                                               ushort_t* __restrict__ oh,
                                               ushort_t* __restrict__ ol, int N) {
  int wid = threadIdx.x >> 6;
  int l = threadIdx.x & 63;
  int n = blockIdx.x * 4 + wid;
  if (n >= N) return;
  int beg = ptr[n];
  int deg = ptr[n + 1] - beg;
  long obase = (long)n * 256 + l * 4;
  float4 acc = make_float4(0.f, 0.f, 0.f, 0.f);
  if (deg > 0) {
    int hh = l & 7;
    int eo = l >> 3;
    int hg = l >> 3;
    float erv = er[(long)n * 8 + hh];
    if (deg <= 64) {
      int sid = (l < deg) ? adj[beg + l] : 0;
      int npass = (deg + 7) >> 3;
      float v[8];
      float m = -1e30f;
      #pragma unroll
      for (int p = 0; p < 8; ++p) {
        if (p < npass) {
          int e = p * 8 + eo;
          int s = __shfl(sid, e);
          float vv = -1e30f;
          if (e < deg) {
            vv = el[(long)s * 8 + hh] + erv;
            vv = vv > 0.f ? vv : LEAKY * vv;
          }
          v[p] = vv;
          m = fmaxf(m, vv);
        }
      }
      m = fmaxf(m, __shfl_xor(m, 8));
      m = fmaxf(m, __shfl_xor(m, 16));
      m = fmaxf(m, __shfl_xor(m, 32));
      float ssum = 0.f;
      #pragma unroll
      for (int p = 0; p < 8; ++p) {
        if (p < npass) {
          float ex = (p * 8 + eo < deg) ? __expf(v[p] - m) : 0.f;
          v[p] = ex;
          ssum += ex;
        }
      }
      ssum += __shfl_xor(ssum, 8);
      ssum += __shfl_xor(ssum, 16);
      ssum += __shfl_xor(ssum, 32);
      float inv = 1.0f / ssum;
      #pragma unroll
      for (int p = 0; p < 8; ++p) {
        if (p < npass) {
          v[p] *= inv;
          #pragma unroll
          for (int e2 = 0; e2 < 8; ++e2) {
            int e = p * 8 + e2;
            if (e < deg) {
              float a = __shfl(v[p], (e2 << 3) | hg);
              int s = __shfl(sid, e);
              const ushort4 hv = *(const ushort4*)(hb + (long)s * 256 + l * 4);
              acc.x += a * bf2f(hv.x);
              acc.y += a * bf2f(hv.y);
              acc.z += a * bf2f(hv.z);
              acc.w += a * bf2f(hv.w);
            }
          }
        }
      }
    } else {
      float m = -1e30f;
      for (int base = 0; base < deg; base += 8) {
        int e = base + eo;
        float vv = -1e30f;
        if (e < deg) {
          int s = adj[beg + e];
          vv = el[(long)s * 8 + hh] + erv;
          vv = vv > 0.f ? vv : LEAKY * vv;
        }
        m = fmaxf(m, vv);
      }
      m = fmaxf(m, __shfl_xor(m, 8));
      m = fmaxf(m, __shfl_xor(m, 16));
      m = fmaxf(m, __shfl_xor(m, 32));
      float ssum = 0.f;
      for (int base = 0; base < deg; base += 8) {
        int e = base + eo;
        if (e < deg) {
          int s = adj[beg + e];
          float vv = el[(long)s * 8 + hh] + erv;
          vv = vv > 0.f ? vv : LEAKY * vv;
          ssum += __expf(vv - m);
        }
      }
      ssum += __shfl_xor(ssum, 8);
      ssum += __shfl_xor(ssum, 16);
      ssum += __shfl_xor(ssum, 32);
      float inv = 1.0f / ssum;
      for (int base = 0; base < deg; base += 8) {
        int e = base + eo;
        float a_me = 0.f;
        int s_me = 0;
        if (e < deg) {
          s_me = adj[beg + e];
          float vv = el[(long)s_me * 8 + hh] + erv;
          vv = vv > 0.f ? vv : LEAKY * vv;
          a_me = __expf(vv - m) * inv;
        }
        #pragma unroll
        for (int e2 = 0; e2 < 8; ++e2) {
          int e3 = base + e2;
          if (e3 < deg) {
            int srcl = (e2 << 3) | hg;
            float a = __shfl(a_me, srcl);
            int s = __shfl(s_me, srcl);
            const ushort4 hv = *(const ushort4*)(hb + (long)s * 256 + l * 4);
            acc.x += a * bf2f(hv.x);
            acc.y += a * bf2f(hv.y);
            acc.z += a * bf2f(hv.z);
            acc.w += a * bf2f(hv.w);
          }
        }
      }
    }
  }
  if (SPLIT) {
    unsigned short hx = f2bf(acc.x), hy = f2bf(acc.y), hz = f2bf(acc.z), hw = f2bf(acc.w);
    ushort4 hi = make_ushort4(hx, hy, hz, hw);
    ushort4 lo = make_ushort4(f2bf(acc.x - bf2f(hx)), f2bf(acc.y - bf2f(hy)),
                              f2bf(acc.z - bf2f(hz)), f2bf(acc.w - bf2f(hw)));
    *(ushort4*)(oh + obase) = hi;
    *(ushort4*)(ol + obase) = lo;
  } else {
    *(float4*)(outf + obase) = acc;
  }
}

// ---------------- fused pool + MLP ----------------
__device__ __forceinline__ int lower_bound_i(const int* a, int n, int key) {
  int lo = 0, hi = n;
  while (lo < hi) {
    int mid = (lo + hi) >> 1;
    if (a[mid] < key) lo = mid + 1; else hi = mid;
  }
  return lo;
}

__global__ __launch_bounds__(256) void poolmlp_k(const float* __restrict__ h,
                                                 const int* __restrict__ gid,
                                                 const float* __restrict__ Wd1,
                                                 const float* __restrict__ bd1,
                                                 const float* __restrict__ Wd2,
                                                 const float* __restrict__ bd2,
                                                 float* __restrict__ outv, int N, int G) {
  int g = blockIdx.x;
  int t = threadIdx.x;
  __shared__ int s_lo, s_hi;
  if (t == 0) {
    s_lo = lower_bound_i(gid, N, g);
    s_hi = lower_bound_i(gid, N, g + 1);
  }
  __syncthreads();
  int lo = s_lo, hi = s_hi;
  float acc = 0.f;
  for (int n = lo; n < hi; ++n) acc += h[(long)n * 256 + t];
  float c = (float)(hi - lo);
  __shared__ float p_s[256];
  __shared__ float red[256];
  p_s[t] = acc / fmaxf(c, 1.f);
  __syncthreads();
  float acc0 = bd1[t], acc1 = bd1[t + 256];
  for (int k = 0; k < 256; ++k) {
    float pv = p_s[k];
    acc0 += pv * Wd1[k * 512 + t];
    acc1 += pv * Wd1[k * 512 + t + 256];
  }
  acc0 = fmaxf(acc0, 0.f);
  acc1 = fmaxf(acc1, 0.f);
  red[t] = acc0 * Wd2[t] + acc1 * Wd2[t + 256];
  __syncthreads();
  for (int off = 128; off > 0; off >>= 1) {
    if (t < off) red[t] += red[t + off];
    __syncthreads();
  }
  if (t == 0) outv[g] = red[0] + bd2[0];
}

extern "C" void kernel_launch(void* const* d_in, const int* in_sizes, int n_in,
                              void* d_out, int out_size, void* d_ws, size_t ws_size,
                              hipStream_t stream) {
  const float* X   = (const float*)d_in[0];
  const int*   src = (const int*)d_in[1];
  const int*   dst = (const int*)d_in[2];
  const int*   gid = (const int*)d_in[3];
  const float* W0  = (const float*)d_in[5];
  const float* al0 = (const float*)d_in[6];
  const float* ar0 = (const float*)d_in[7];
  const float* W1  = (const float*)d_in[8];
  const float* al1 = (const float*)d_in[9];
  const float* ar1 = (const float*)d_in[10];
  const float* Wd1 = (const float*)d_in[11];
  const float* bd1 = (const float*)d_in[12];
  const float* Wd2 = (const float*)d_in[13];
  const float* bd2 = (const float*)d_in[14];

  int E = in_sizes[1];
  int N = in_sizes[3];
  int G = out_size;

  // Region R1: Xh/Xl (phase 1) -> Ah/Al (phase 2) -> bAgg f32 (phase 3); disjoint lifetimes.
  char* w = (char*)d_ws;
  ushort_t* Xh   = (ushort_t*)w;                   // [N*128]
  ushort_t* Xl   = Xh + (size_t)N * 128;           // [N*128]
  ushort_t* Ah   = (ushort_t*)w;                   // [N*256]
  ushort_t* Al   = Ah + (size_t)N * 256;           // [N*256]
  float*    bAgg = (float*)w;                      // [N*256] f32
  char* p = w + (size_t)N * 256 * 4;
  ushort_t* hb   = (ushort_t*)p; p += (size_t)N * 256 * 2;   // [N,256] bf16 h
  float*    el   = (float*)p;    p += (size_t)N * 8 * 4;
  float*    er   = (float*)p;    p += (size_t)N * 8 * 4;
  ushort_t* W0h  = (ushort_t*)p; p += (size_t)256 * 128 * 2;
  ushort_t* W1h  = (ushort_t*)p; p += (size_t)256 * 256 * 2;
  int*      ptr  = (int*)p;      p += (size_t)(N + 1) * 4;
  int*      cnt  = (int*)p;      p += (size_t)N * 4;
  int*      adj  = (int*)p;      p += (size_t)E * 4;
  int*      bsum = (int*)p;

  int nb = (N + 1023) / 1024;

  // CSR build over dst (adj stores src values)
  hipMemsetAsync(cnt, 0, (size_t)N * 4, stream);
  count_k<<<(E + 255) / 256, 256, 0, stream>>>(dst, cnt, E);
  scan1_k<<<nb, 1024, 0, stream>>>(cnt, ptr, bsum, N);  // also zeroes cnt
  scan2_k<<<1, 64, 0, stream>>>(bsum, nb);
  scan3_k<<<nb, 1024, 0, stream>>>(ptr, bsum, N, E);
  fill_k<<<(E + 255) / 256, 256, 0, stream>>>(dst, src, ptr, cnt, adj, E);

  // weight + input splits
  whsplit_k<<<(256 * 128 + 255) / 256, 256, 0, stream>>>(W0, W0h, 128);
  whsplit_k<<<(256 * 256 + 255) / 256, 256, 0, stream>>>(W1, W1h, 256);
  asplit_k<<<(int)(((long)N * 128 / 4 + 255) / 256), 256, 0, stream>>>(X, Xh, Xl, (long)N * 128);

  dim3 gg(N / 128, 2);
  // layer 0 (gemm writes hb + el/er fused)
  gemm3_k<<<gg, 256, 0, stream>>>(Xh, Xl, W0h, al0, ar0, hb, el, er, N, 128);
  agg_t_k<1><<<(N + 3) / 4, 256, 0, stream>>>(hb, el, er, ptr, adj, (float*)nullptr, Ah, Al, N);
  // layer 1
  gemm3_k<<<gg, 256, 0, stream>>>(Ah, Al, W1h, al1, ar1, hb, el, er, N, 256);
  agg_t_k<0><<<(N + 3) / 4, 256, 0, stream>>>(hb, el, er, ptr, adj, bAgg, (ushort_t*)nullptr, (ushort_t*)nullptr, N);
  // readout + MLP (fused)
  poolmlp_k<<<G, 256, 0, stream>>>(bAgg, gid, Wd1, bd1, Wd2, bd2, (float*)d_out, N, G);
}